// Round 8
// baseline (3398.226 us; speedup 1.0000x reference)
//
#include <hip/hip_runtime.h>
#include <hip/hip_bf16.h>

// ELA forward on MI355X.
//  pack_x           : x fp32 -> bf16 seq in MFMA A-fragment tile order (staged in d_out)
//  pack_B           : {W} fp32 -> bf16 MFMA B-fragment [nb][kc] tile order (for pre_gemm)
//  pack_R           : {R} fp32 -> bf16 B-fragments, UNIT-CONTIGUOUS [nt][kc][i][lane][8]
//  pre_gemm_packed  : pre = seq @ W{1,2}; all-bf16, global_load_lds both operands
//  persistent_step  : ONE coop kernel, 192 blocks x 512 thr (round-6-proven geometry),
//                     all 48 steps. Per wave: 8 of 24 kc of R STATIONARY in VGPRs
//                     (1/3 of R never re-read); rest streamed via NORMAL cached loads.
//                     h + barrier use SYSTEM-scope RELAXED atomics (straight to L3,
//                     no acquire/threadfence -> no L2 invalidate -> R stays L2-warm).
//                     Bounded spin (cannot hang). c/n/m state in registers.
//  step_kernel x48  : fallback path if cooperative launch unavailable.
//  conv_gn_kernel   : grouped conv1d + GroupNorm + sigmoid
//  final_kernel     : out = xh[b,c,i] * xw[b,c,j] * x[b,c,i,j]
//
// HARD CONSTRAINTS (learned):
//  - round 1: NEVER write input buffers (d_in[*]) — harness replays without restoring.
//  - round 4: cg::grid.sync ~93us/sync. round 5: >256-block coop + unbounded spin hangs.
//  - round 6: threadfence/acquire barriers invalidate per-XCD L2 -> R refetches from HBM
//    every step (75MB/step fetch, 101us/step). Coherence must be h-only, via L3.

typedef float  f32x4 __attribute__((ext_vector_type(4)));
typedef __bf16 v8bf  __attribute__((ext_vector_type(8)));
typedef __bf16 v4bf  __attribute__((ext_vector_type(4)));

#define MFMA16(a, b, c) __builtin_amdgcn_mfma_f32_16x16x32_bf16((a), (b), (c), 0, 0, 0)

// ---- ws layout (bytes). Base block = 40.1 MB. Packs appended (ws >= 191MB verified). ----
static constexpr size_t OFF_PREP = 0;            // bf16 pre, C-frag order: 2*48*768*64*4
static constexpr size_t SZ_PREP  = 37748736;
static constexpr size_t OFF_H0   = 37748736;     // h ping (A-frag, 2 stacks): 2*96*64*8*2
static constexpr size_t OFF_H1   = 37945344;     // h pong
static constexpr size_t OFF_C    = 38141952;     // c state fp32 (fallback path only)
static constexpr size_t OFF_N    = 38535168;
static constexpr size_t OFF_M    = 38928384;
static constexpr size_t OFF_YS   = 39321600;     // y sums fp32: 2*16*3072*4
static constexpr size_t OFF_GATE = 39714816;     // sigmoid gates fp32 (also: barrier word)
static constexpr size_t BASE_END = 40108032;
static constexpr size_t SZ_RPACK = 75497472;     // one packed 3072x12288 bf16
static constexpr size_t OFF_RA   = BASE_END;     // W-pack lives here first, then R-pack
static constexpr size_t OFF_RB   = BASE_END + SZ_RPACK;
static constexpr size_t END_A    = OFF_RB + SZ_RPACK;   // 191,102,976

__device__ __forceinline__ void gl_lds16(const void* g, void* l) {
    __builtin_amdgcn_global_load_lds(
        (const __attribute__((address_space(1))) unsigned int*)g,
        (__attribute__((address_space(3))) unsigned int*)l, 16, 0, 0);
}

__global__ __launch_bounds__(256) void zero_kernel(f32x4* __restrict__ p, int n) {
    int i = blockIdx.x * 256 + threadIdx.x;
    if (i < n) { f32x4 z = 0.0f; p[i] = z; }
}

// x[16,64,48,48] -> seq A-pack: [mb 6][kc 96][sub 8][lane 64][8] bf16, row r = t*16+b
__global__ __launch_bounds__(256) void pack_x_kernel(const float* __restrict__ x,
                                                     __bf16* __restrict__ dst) {
    int gi = blockIdx.x * 256 + threadIdx.x;   // < 294912
    int lane = gi & 63;
    int rest = gi >> 6;
    int sub = rest & 7; rest >>= 3;
    int kc = rest % 96, mb = rest / 96;
    int r = mb * 128 + sub * 16 + (lane & 15);
    int t = r >> 4, b = r & 15;
    int k = kc * 32 + (lane >> 4) * 8;
    const f32x4* s = (const f32x4*)(x + (size_t)b * 147456 + (size_t)t * 3072 + k);
    f32x4 v0 = s[0], v1 = s[1];
    v8bf o;
#pragma unroll
    for (int j = 0; j < 4; ++j) { o[j] = (__bf16)v0[j]; o[4 + j] = (__bf16)v1[j]; }
    ((v8bf*)dst)[gi] = o;
}

// [3072,12288] fp32 -> B-pack [nb 96][kc 96][sub 8][lane 64][8] bf16 (via LDS transpose)
__global__ __launch_bounds__(256) void pack_B_kernel(const float* __restrict__ src0,
                                                     const float* __restrict__ src1,
                                                     __bf16* __restrict__ dst0,
                                                     __bf16* __restrict__ dst1) {
    int nb = blockIdx.x, kc = blockIdx.y, m = blockIdx.z;
    const float* src = m ? src1 : src0;
    __bf16* dst = m ? dst1 : dst0;
    int tid = threadIdx.x;
    __shared__ float tile[32][133];
    int kr = tid >> 3, nc0 = (tid & 7) * 16;
    const f32x4* s4 = (const f32x4*)(src + (size_t)(kc * 32 + kr) * 12288 + nb * 128 + nc0);
    f32x4 v0 = s4[0], v1 = s4[1], v2 = s4[2], v3 = s4[3];
#pragma unroll
    for (int r = 0; r < 4; ++r) {
        tile[kr][nc0 + r]      = v0[r];
        tile[kr][nc0 + 4 + r]  = v1[r];
        tile[kr][nc0 + 8 + r]  = v2[r];
        tile[kr][nc0 + 12 + r] = v3[r];
    }
    __syncthreads();
    __bf16* db = dst + (size_t)(nb * 96 + kc) * 4096;
#pragma unroll
    for (int c = 0; c < 2; ++c) {
        int lidx = tid * 2 + c;
        int sub = lidx >> 6, lane = lidx & 63;
        int kb = (lane >> 4) * 8, nn = sub * 16 + (lane & 15);
        v8bf o;
#pragma unroll
        for (int j = 0; j < 8; ++j) o[j] = (__bf16)tile[kb + j][nn];
        ((v8bf*)db)[lidx] = o;
    }
}

// [3072,12288] fp32 -> R-pack, UNIT-CONTIGUOUS: v8bf index ((nt*96+kc)*4+i)*64+lane,
// where column-tile ct = nb*8+sub = i*192+nt.
__global__ __launch_bounds__(256) void pack_R_kernel(const float* __restrict__ src0,
                                                     const float* __restrict__ src1,
                                                     __bf16* __restrict__ dst0,
                                                     __bf16* __restrict__ dst1) {
    int nb = blockIdx.x, kc = blockIdx.y, m = blockIdx.z;
    const float* src = m ? src1 : src0;
    __bf16* dst = m ? dst1 : dst0;
    int tid = threadIdx.x;
    __shared__ float tile[32][133];
    int kr = tid >> 3, nc0 = (tid & 7) * 16;
    const f32x4* s4 = (const f32x4*)(src + (size_t)(kc * 32 + kr) * 12288 + nb * 128 + nc0);
    f32x4 v0 = s4[0], v1 = s4[1], v2 = s4[2], v3 = s4[3];
#pragma unroll
    for (int r = 0; r < 4; ++r) {
        tile[kr][nc0 + r]      = v0[r];
        tile[kr][nc0 + 4 + r]  = v1[r];
        tile[kr][nc0 + 8 + r]  = v2[r];
        tile[kr][nc0 + 12 + r] = v3[r];
    }
    __syncthreads();
#pragma unroll
    for (int c = 0; c < 2; ++c) {
        int lidx = tid * 2 + c;
        int sub = lidx >> 6, lane = lidx & 63;
        int kb = (lane >> 4) * 8, nn = sub * 16 + (lane & 15);
        v8bf o;
#pragma unroll
        for (int j = 0; j < 8; ++j) o[j] = (__bf16)tile[kb + j][nn];
        int ct = nb * 8 + sub;
        int nt = ct % 192, fi = ct / 192;
        size_t off = (((size_t)nt * 96 + kc) * 4 + fi) * 64 + lane;
        ((v8bf*)dst)[off] = o;
    }
}

// pre = seq @ W, 128x128 tile, BK=32, BOTH operands pre-packed bf16 via global_load_lds.
__global__ __launch_bounds__(256) void pre_gemm_packed(const __bf16* __restrict__ Apack,
                                                       const __bf16* __restrict__ Bp0,
                                                       const __bf16* __restrict__ Bp1,
                                                       __bf16* __restrict__ preP) {
    int nb = blockIdx.x, mb = blockIdx.y, stack = blockIdx.z;
    const char* Bpack = (const char*)(stack ? Bp1 : Bp0);
    int tid = threadIdx.x, wave = tid >> 6, lane = tid & 63;
    __shared__ alignas(16) __bf16 As[4096];
    __shared__ alignas(16) __bf16 Bs[4096];
    f32x4 acc[4][4];
#pragma unroll
    for (int i = 0; i < 4; ++i)
#pragma unroll
        for (int j = 0; j < 4; ++j) acc[i][j] = 0.0f;

    for (int kc = 0; kc < 96; ++kc) {
        size_t atile = (size_t)(mb * 96 + kc) * 8192;
        size_t btile = (size_t)(nb * 96 + kc) * 8192;
        int chunk = wave * 2048;
        gl_lds16((const char*)Apack + atile + chunk + lane * 16,        (char*)As + chunk);
        gl_lds16((const char*)Apack + atile + chunk + 1024 + lane * 16, (char*)As + chunk + 1024);
        gl_lds16(Bpack + btile + chunk + lane * 16,        (char*)Bs + chunk);
        gl_lds16(Bpack + btile + chunk + 1024 + lane * 16, (char*)Bs + chunk + 1024);
        __syncthreads();
        const v8bf* A8 = (const v8bf*)As;
        const v8bf* B8 = (const v8bf*)Bs;
        v8bf a[4], b[4];
#pragma unroll
        for (int mi = 0; mi < 4; ++mi) a[mi] = A8[((wave >> 1) * 4 + mi) * 64 + lane];
#pragma unroll
        for (int ni = 0; ni < 4; ++ni) b[ni] = B8[((wave & 1) * 4 + ni) * 64 + lane];
#pragma unroll
        for (int mi = 0; mi < 4; ++mi)
#pragma unroll
            for (int ni = 0; ni < 4; ++ni) acc[mi][ni] = MFMA16(a[mi], b[ni], acc[mi][ni]);
        __syncthreads();
    }
#pragma unroll
    for (int mi = 0; mi < 4; ++mi)
#pragma unroll
        for (int ni = 0; ni < 4; ++ni) {
            int mt = mb * 8 + (wave >> 1) * 4 + mi;   // == t
            int nt4 = nb * 8 + (wave & 1) * 4 + ni;   // n-tile in [0,768)
            v4bf o;
#pragma unroll
            for (int r = 0; r < 4; ++r) o[r] = (__bf16)acc[mi][ni][r];
            ((v4bf*)preP)[(((size_t)stack * 48 + mt) * 768 + nt4) * 64 + lane] = o;
        }
}

// Fallback (small ws): pre = seq @ W with W read as fp32 (transpose+cvt in LDS).
__global__ __launch_bounds__(256) void pre_gemm(const __bf16* __restrict__ Apack,
                                                const float* __restrict__ W1,
                                                const float* __restrict__ W2,
                                                __bf16* __restrict__ preP) {
    int nb = blockIdx.x, mb = blockIdx.y, stack = blockIdx.z;
    const float* W = stack ? W2 : W1;
    int tid = threadIdx.x, wave = tid >> 6, lane = tid & 63;
    __shared__ alignas(16) __bf16 As[4096];
    __shared__ alignas(16) __bf16 Bs[4096];
    __shared__ float tile[32][133];
    f32x4 acc[4][4];
#pragma unroll
    for (int i = 0; i < 4; ++i)
#pragma unroll
        for (int j = 0; j < 4; ++j) acc[i][j] = 0.0f;

    int kr = tid >> 3, nc0 = (tid & 7) * 16;
    for (int kc = 0; kc < 96; ++kc) {
        size_t atile = (size_t)(mb * 96 + kc) * 8192;
        int chunk = wave * 2048;
        gl_lds16((const char*)Apack + atile + chunk + lane * 16,        (char*)As + chunk);
        gl_lds16((const char*)Apack + atile + chunk + 1024 + lane * 16, (char*)As + chunk + 1024);
        const f32x4* s4 = (const f32x4*)(W + (size_t)(kc * 32 + kr) * 12288 + nb * 128 + nc0);
        f32x4 v0 = s4[0], v1 = s4[1], v2 = s4[2], v3 = s4[3];
#pragma unroll
        for (int r = 0; r < 4; ++r) {
            tile[kr][nc0 + r]      = v0[r];
            tile[kr][nc0 + 4 + r]  = v1[r];
            tile[kr][nc0 + 8 + r]  = v2[r];
            tile[kr][nc0 + 12 + r] = v3[r];
        }
        __syncthreads();
#pragma unroll
        for (int c = 0; c < 2; ++c) {
            int lidx = tid * 2 + c;
            int sub = lidx >> 6, l2 = lidx & 63;
            int kb = (l2 >> 4) * 8, nn = sub * 16 + (l2 & 15);
            v8bf o;
#pragma unroll
            for (int j = 0; j < 8; ++j) o[j] = (__bf16)tile[kb + j][nn];
            ((v8bf*)Bs)[lidx] = o;
        }
        __syncthreads();
        const v8bf* A8 = (const v8bf*)As;
        const v8bf* B8 = (const v8bf*)Bs;
        v8bf a[4], b[4];
#pragma unroll
        for (int mi = 0; mi < 4; ++mi) a[mi] = A8[((wave >> 1) * 4 + mi) * 64 + lane];
#pragma unroll
        for (int ni = 0; ni < 4; ++ni) b[ni] = B8[((wave & 1) * 4 + ni) * 64 + lane];
#pragma unroll
        for (int mi = 0; mi < 4; ++mi)
#pragma unroll
            for (int ni = 0; ni < 4; ++ni) acc[mi][ni] = MFMA16(a[mi], b[ni], acc[mi][ni]);
        __syncthreads();
    }
#pragma unroll
    for (int mi = 0; mi < 4; ++mi)
#pragma unroll
        for (int ni = 0; ni < 4; ++ni) {
            int mt = mb * 8 + (wave >> 1) * 4 + mi;
            int nt4 = nb * 8 + (wave & 1) * 4 + ni;
            v4bf o;
#pragma unroll
            for (int r = 0; r < 4; ++r) o[r] = (__bf16)acc[mi][ni][r];
            ((v4bf*)preP)[(((size_t)stack * 48 + mt) * 768 + nt4) * 64 + lane] = o;
        }
}

// ---------------- persistent recurrence: VGPR-stationary R + L2-warm streaming ----------------
// 192 blocks x 512 thr (round-6-proven coop geometry; 1 block/CU, 2 waves/SIMD -> 256 VGPR).
// Block nt: unit (stack0, nt) on waves 0-3, unit (stack1, nt) on waves 4-7; 24 kc/wave.
// Last 8 kc of each wave held in registers for all 48 steps; first 16 streamed (cached).
// h and the barrier use system-scope RELAXED atomics only -> no L2 invalidation, ever.
__global__ __launch_bounds__(512, 2) void persistent_step(
    const __bf16* __restrict__ Rp0, const __bf16* __restrict__ Rp1,
    __bf16* __restrict__ h0, __bf16* __restrict__ h1,
    const __bf16* __restrict__ preP,
    const float* __restrict__ bias1, const float* __restrict__ bias2,
    float* __restrict__ ysum, unsigned* __restrict__ bar) {
    int nt = blockIdx.x;                       // [0,192)
    int tid = threadIdx.x, wave = tid >> 6, lane = tid & 63;
    int s  = wave >> 2;                        // unit stack
    int wv = wave & 3;                         // K-split index within unit
    const v8bf* Rp = (const v8bf*)(s ? Rp1 : Rp0);
    size_t base0 = (size_t)nt * 24576 + lane;  // unit slice start (v8bf units)
    int kcs = wv * 24;
    const float* bias = s ? bias2 : bias1;
    int fcol = nt * 16 + (lane & 15);
    int bq = (lane >> 4) * 4;
    int kc2 = fcol >> 5, ko = fcol & 31;
    float* yb = ysum + (size_t)s * 16 * 3072;

    // stationary R: kc = kcs+16 .. kcs+23 (8 kc x 4 frags = 128 VGPRs payload)
    v8bf rS[8][4];
#pragma unroll
    for (int j = 0; j < 8; ++j)
#pragma unroll
        for (int i = 0; i < 4; ++i)
            rS[j][i] = Rp[base0 + (size_t)(kcs + 16 + j) * 256 + i * 64];

    f32x4 cc = 0.0f, nn = 0.0f, mm = 0.0f;     // register-resident sLSTM state (waves 0,4)
    const __bf16* hr = h0;
    __bf16* hwp = h1;

    __shared__ f32x4 red[2][4][4][64];         // [unit][wv][frag][lane]

    for (int t = 0; t < 48; ++t) {
        // ---- phase A: G-partial = h @ R ----
        const unsigned long long* hq = (const unsigned long long*)hr + (size_t)s * 12288;
        f32x4 acc[4];
#pragma unroll
        for (int i = 0; i < 4; ++i) acc[i] = 0.0f;
#pragma unroll
        for (int kk = 0; kk < 24; ++kk) {
            int kc = kcs + kk;
            size_t qi = ((size_t)kc * 64 + lane) * 2;
            unsigned long long q0 = __hip_atomic_load(hq + qi,     __ATOMIC_RELAXED,
                                                      __HIP_MEMORY_SCOPE_SYSTEM);
            unsigned long long q1 = __hip_atomic_load(hq + qi + 1, __ATOMIC_RELAXED,
                                                      __HIP_MEMORY_SCOPE_SYSTEM);
            unsigned long long tmp[2] = {q0, q1};
            v8bf a; __builtin_memcpy(&a, tmp, 16);
            if (kk < 16) {
#pragma unroll
                for (int i = 0; i < 4; ++i) {
                    v8bf b = Rp[base0 + (size_t)kc * 256 + i * 64];
                    acc[i] = MFMA16(a, b, acc[i]);
                }
            } else {
#pragma unroll
                for (int i = 0; i < 4; ++i)
                    acc[i] = MFMA16(a, rS[kk - 16][i], acc[i]);
            }
        }
#pragma unroll
        for (int i = 0; i < 4; ++i) red[s][wv][i][lane] = acc[i];
        __syncthreads();

        // ---- phase B: gates on waves 0 (stack0) and 4 (stack1) ----
        if (wv == 0) {
            f32x4 g[4];
#pragma unroll
            for (int i = 0; i < 4; ++i) {
                f32x4 sum = red[s][0][i][lane];
#pragma unroll
                for (int w = 1; w < 4; ++w) sum += red[s][w][i][lane];
                g[i] = sum;
            }
#pragma unroll
            for (int i = 0; i < 4; ++i) {
                v4bf pv = ((const v4bf*)preP)[(((size_t)s * 48 + t) * 768 + (i * 192 + nt)) * 64 + lane];
                float bv = bias[i * 3072 + fcol];
#pragma unroll
                for (int r = 0; r < 4; ++r) g[i][r] += (float)pv[r] + bv;
            }
            __bf16* hwB = hwp + ((size_t)s * 96 + kc2) * 512 + (size_t)(ko >> 3) * 128 + (ko & 7);
            int flat = t * 3072 + fcol;
            int cch = flat / 2304;
            int rem = flat - cch * 2304;
            int uu = rem / 48;
            int vv = rem - uu * 48;
            int yidx = cch * 48 + (s ? uu : vv);
#pragma unroll
            for (int r = 0; r < 4; ++r) {
                int brow = bq + r;
                float it = g[0][r], ft = g[1][r], zt = g[2][r], ot = g[3][r];
                float mnew = fmaxf(ft + mm[r], it);
                float iv = __expf(it - mnew);
                float fv = __expf(ft + mm[r] - mnew);
                float cnew = fv * cc[r] + iv * tanhf(zt);
                float nnew = fv * nn[r] + iv;
                float sg = 1.0f / (1.0f + __expf(-ot));
                float h = sg * cnew / (nnew + 1e-6f);
                cc[r] = cnew; nn[r] = nnew; mm[r] = mnew;
                __bf16 hb = (__bf16)h;
                unsigned short hs; __builtin_memcpy(&hs, &hb, 2);
                __hip_atomic_store((unsigned short*)(hwB + (size_t)brow * 8), hs,
                                   __ATOMIC_RELAXED, __HIP_MEMORY_SCOPE_SYSTEM);
                atomicAdd(yb + (size_t)brow * 3072 + yidx, h);
            }
        }

        // ---- grid barrier: system-scope relaxed counter, bounded spin ----
        // (__syncthreads drains each wave's vmcnt first -> all h stores are at L3
        //  before tid 0 increments; spin loads go straight to L3, no L2 invalidate.)
        __syncthreads();
        if (tid == 0) {
            __hip_atomic_fetch_add(bar, 1u, __ATOMIC_RELAXED, __HIP_MEMORY_SCOPE_SYSTEM);
            unsigned tgt = (unsigned)(t + 1) * 192u;
            int guard = 0;
            while (__hip_atomic_load(bar, __ATOMIC_RELAXED, __HIP_MEMORY_SCOPE_SYSTEM) < tgt) {
                __builtin_amdgcn_s_sleep(2);
                if (++guard > 50000) break;    // safety valve: fail fast, never hang
            }
        }
        __syncthreads();

        const __bf16* tmp = hr; hr = hwp; hwp = (__bf16*)tmp;
    }
}

// ---------------- fallback: one launch per step (rounds 0/2/3/7 verified) ----------------
__global__ __launch_bounds__(512) void step_kernel(
    const __bf16* __restrict__ Rp0, const __bf16* __restrict__ Rp1,
    const __bf16* __restrict__ hread, __bf16* __restrict__ hwrite,
    const __bf16* __restrict__ preP,
    const float* __restrict__ bias1, const float* __restrict__ bias2,
    float* __restrict__ cbuf, float* __restrict__ nbuf, float* __restrict__ mbuf,
    float* __restrict__ ysum, int t) {
    int nt = blockIdx.x, stack = blockIdx.y;
    int tid = threadIdx.x, wave = tid >> 6, lane = tid & 63;
    const v8bf* Rp = (const v8bf*)(stack ? Rp1 : Rp0);
    const v8bf* hA = (const v8bf*)hread + (size_t)stack * 96 * 64;
    size_t base0 = (size_t)nt * 24576 + lane;
    int kcs = wave * 12;
    f32x4 acc[4];
#pragma unroll
    for (int i = 0; i < 4; ++i) acc[i] = 0.0f;
#pragma unroll 4
    for (int kk = 0; kk < 12; ++kk) {
        int kc = kcs + kk;
        v8bf a = hA[(size_t)kc * 64 + lane];
        v8bf bb[4];
#pragma unroll
        for (int i = 0; i < 4; ++i) bb[i] = Rp[base0 + (size_t)kc * 256 + i * 64];
#pragma unroll
        for (int i = 0; i < 4; ++i) acc[i] = MFMA16(a, bb[i], acc[i]);
    }

    __shared__ f32x4 red4[8][4][64];
#pragma unroll
    for (int i = 0; i < 4; ++i) red4[wave][i][lane] = acc[i];
    __syncthreads();

    if (wave == 0) {
        const float* bias = stack ? bias2 : bias1;
        f32x4 g[4];
#pragma unroll
        for (int i = 0; i < 4; ++i) {
            f32x4 s = red4[0][i][lane];
#pragma unroll
            for (int w = 1; w < 8; ++w) s += red4[w][i][lane];
            g[i] = s;
        }
        int fcol = nt * 16 + (lane & 15);
        int bq = (lane >> 4) * 4;
#pragma unroll
        for (int i = 0; i < 4; ++i) {
            v4bf pv = ((const v4bf*)preP)[(((size_t)stack * 48 + t) * 768 + (i * 192 + nt)) * 64 + lane];
            float bv = bias[i * 3072 + fcol];
#pragma unroll
            for (int r = 0; r < 4; ++r) g[i][r] += (float)pv[r] + bv;
        }
        size_t sidx = ((size_t)stack * 192 + nt) * 64 + lane;
        f32x4 cc = ((f32x4*)cbuf)[sidx];
        f32x4 nn = ((f32x4*)nbuf)[sidx];
        f32x4 mm = ((f32x4*)mbuf)[sidx];
        int kc = fcol >> 5, ko = fcol & 31;
        __bf16* hw = hwrite + ((size_t)stack * 96 + kc) * 512 + (size_t)(ko >> 3) * 128 + (ko & 7);
        int flat = t * 3072 + fcol;
        int cch = flat / 2304;
        int rem = flat - cch * 2304;
        int uu = rem / 48;
        int vv = rem - uu * 48;
        int yidx = cch * 48 + (stack ? uu : vv);
        float* yb = ysum + (size_t)stack * 16 * 3072;
#pragma unroll
        for (int r = 0; r < 4; ++r) {
            int brow = bq + r;
            float it = g[0][r], ft = g[1][r], zt = g[2][r], ot = g[3][r];
            float mnew = fmaxf(ft + mm[r], it);
            float iv = __expf(it - mnew);
            float fv = __expf(ft + mm[r] - mnew);
            float cnew = fv * cc[r] + iv * tanhf(zt);
            float nnew = fv * nn[r] + iv;
            float sg = 1.0f / (1.0f + __expf(-ot));
            float h = sg * cnew / (nnew + 1e-6f);
            cc[r] = cnew; nn[r] = nnew; mm[r] = mnew;
            hw[(size_t)brow * 8] = (__bf16)h;
            atomicAdd(yb + (size_t)brow * 3072 + yidx, h);
        }
        ((f32x4*)cbuf)[sidx] = cc;
        ((f32x4*)nbuf)[sidx] = nn;
        ((f32x4*)mbuf)[sidx] = mm;
    }
}

// grouped conv1d (K=5, 8 groups of 8ch) + GroupNorm(16 groups) + sigmoid, per (which, b)
__global__ __launch_bounds__(256) void conv_gn_kernel(const float* __restrict__ ysum,
                                                      const float* __restrict__ cw,
                                                      const float* __restrict__ gamma,
                                                      const float* __restrict__ beta,
                                                      float* __restrict__ gatebuf) {
    int bi = blockIdx.x;
    int s = bi >> 4, b = bi & 15;
    int tid = threadIdx.x;
    __shared__ float in0[3072], cvout[3072], cws[2560];
    __shared__ float r1[16][16], r2[16][16], mu_s[16], rs_s[16];
    const float* src = ysum + (size_t)(s * 16 + b) * 3072;
    for (int e = tid; e < 3072; e += 256) in0[e] = src[e] * (1.0f / 48.0f);
    for (int e = tid; e < 2560; e += 256) cws[e] = cw[e];
    __syncthreads();
    for (int e = tid; e < 3072; e += 256) {
        int co = e / 48, p = e - co * 48;
        int g = co >> 3;
        const float* wrow = cws + co * 40;
        const float* irow = in0 + g * 8 * 48;
        float a = 0.f;
#pragma unroll
        for (int ci = 0; ci < 8; ++ci)
#pragma unroll
            for (int q = 0; q < 5; ++q) {
                int pp = p + q - 2;
                if (pp >= 0 && pp < 48) a += wrow[ci * 5 + q] * irow[ci * 48 + pp];
            }
        cvout[e] = a;
    }
    __syncthreads();
    int gn = tid >> 4, ln = tid & 15;
    float s1 = 0.f, s2 = 0.f;
    for (int ii = ln; ii < 192; ii += 16) {
        float v = cvout[gn * 192 + ii];
        s1 += v; s2 += v * v;
    }
    r1[gn][ln] = s1; r2[gn][ln] = s2;
    __syncthreads();
    if (tid < 16) {
        float a = 0.f, c2 = 0.f;
        for (int ii = 0; ii < 16; ++ii) { a += r1[tid][ii]; c2 += r2[tid][ii]; }
        float mu = a * (1.0f / 192.0f);
        float var = c2 * (1.0f / 192.0f) - mu * mu;
        mu_s[tid] = mu;
        rs_s[tid] = rsqrtf(var + 1e-5f);
    }
    __syncthreads();
    float* dst = gatebuf + (size_t)(s * 16 + b) * 3072;
    for (int e = tid; e < 3072; e += 256) {
        int c = e / 48;
        int gg = c >> 2;
        float xn = (cvout[e] - mu_s[gg]) * rs_s[gg] * gamma[c] + beta[c];
        dst[e] = 1.0f / (1.0f + __expf(-xn));
    }
}

__global__ __launch_bounds__(256) void final_kernel(const float* __restrict__ x,
                                                    const float* __restrict__ gatebuf,
                                                    float* __restrict__ out) {
    int gid = blockIdx.x * 256 + threadIdx.x;  // < 589824 float4s
    int wi4 = gid % 12;
    int rest = gid / 12;
    int hi = rest % 48;
    int bc = rest / 48;
    int b = bc >> 6, c = bc & 63;
    f32x4 xv = ((const f32x4*)x)[gid];
    float gh = gatebuf[(size_t)(16 + b) * 3072 + c * 48 + hi];        // s=1 (y2) -> x_h[hi]
    f32x4 gw = *(const f32x4*)(gatebuf + (size_t)b * 3072 + c * 48 + wi4 * 4);  // s=0 -> x_w[wi]
    f32x4 o;
#pragma unroll
    for (int k = 0; k < 4; ++k) o[k] = xv[k] * gh * gw[k];
    ((f32x4*)out)[gid] = o;
}

extern "C" void kernel_launch(void* const* d_in, const int* in_sizes, int n_in,
                              void* d_out, int out_size, void* d_ws, size_t ws_size,
                              hipStream_t stream) {
    const float* x     = (const float*)d_in[0];
    const float* W1    = (const float*)d_in[1];
    const float* R1    = (const float*)d_in[2];
    const float* b1    = (const float*)d_in[3];
    const float* W2    = (const float*)d_in[4];
    const float* R2    = (const float*)d_in[5];
    const float* b2    = (const float*)d_in[6];
    const float* cw    = (const float*)d_in[7];
    const float* gamma = (const float*)d_in[8];
    const float* beta  = (const float*)d_in[9];

    char* ws = (char*)d_ws;
    __bf16* seqA = (__bf16*)d_out;               // scratch; dead after pre_gemm
    __bf16* preP = (__bf16*)(ws + OFF_PREP);
    __bf16* h0   = (__bf16*)(ws + OFF_H0);
    __bf16* h1   = (__bf16*)(ws + OFF_H1);
    float* cbuf  = (float*)(ws + OFF_C);
    float* nbuf  = (float*)(ws + OFF_N);
    float* mbuf  = (float*)(ws + OFF_M);
    float* ysum  = (float*)(ws + OFF_YS);
    float* gate  = (float*)(ws + OFF_GATE);
    unsigned* bar = (unsigned*)(ws + OFF_GATE);  // barrier word; gate region is fully
                                                 // overwritten only AFTER the steps

    bool big_ws = ws_size >= END_A;   // verified on harness (rounds 0/2/3/4/6/7)
    __bf16* PA = (__bf16*)(ws + OFF_RA);   // pack region (time-shared: W-pack then R-pack)
    __bf16* PB = (__bf16*)(ws + OFF_RB);

    pack_x_kernel<<<1152, 256, 0, stream>>>(x, seqA);
    if (big_ws) {
        pack_B_kernel<<<dim3(96, 96, 2), 256, 0, stream>>>(W1, W2, PA, PB);
        pre_gemm_packed<<<dim3(96, 6, 2), 256, 0, stream>>>(seqA, PA, PB, preP);
        pack_R_kernel<<<dim3(96, 96, 2), 256, 0, stream>>>(R1, R2, PA, PB);
    } else {
        pre_gemm<<<dim3(96, 6, 2), 256, 0, stream>>>(seqA, W1, W2, preP);
        pack_R_kernel<<<dim3(96, 96, 2), 256, 0, stream>>>(R1, R2, PA, PB);
    }
    // zero h0/h1/c/n/m/ysum AND the barrier word (1 extra f32x4 past OFF_GATE start).
    // zero_kernel's end-of-kernel flush publishes the zeros to L3 for the sc1 reads.
    zero_kernel<<<481, 256, 0, stream>>>((f32x4*)(ws + OFF_H0), 122881);

    // Persistent recurrence (VGPR-stationary R, L2-warm streaming, L3-only coherence).
    {
        const __bf16* a0 = PA; const __bf16* a1 = PB;
        __bf16* ph0 = h0; __bf16* ph1 = h1;
        const __bf16* pp = preP;
        const float* pb1 = b1; const float* pb2 = b2;
        float* pys = ysum; unsigned* pbar = bar;
        void* args[] = { (void*)&a0, (void*)&a1, (void*)&ph0, (void*)&ph1,
                         (void*)&pp, (void*)&pb1, (void*)&pb2, (void*)&pys, (void*)&pbar };
        hipError_t err = hipLaunchCooperativeKernel(
            reinterpret_cast<void*>(persistent_step), dim3(192), dim3(512),
            args, 0, stream);
        if (err != hipSuccess) {
            // fallback: classic 48-launch loop (verified rounds 0/2/3/7)
            for (int t = 0; t < 48; ++t) {
                const __bf16* hr = (t & 1) ? h1 : h0;
                __bf16* hw       = (t & 1) ? h0 : h1;
                step_kernel<<<dim3(192, 2), 512, 0, stream>>>(PA, PB, hr, hw, preP, b1, b2,
                                                              cbuf, nbuf, mbuf, ysum, t);
            }
        }
    }

    conv_gn_kernel<<<32, 256, 0, stream>>>(ysum, cw, gamma, beta, gate);
    final_kernel<<<2304, 256, 0, stream>>>(x, gate, (float*)d_out);
}

// Round 9
// 3089.606 us; speedup vs baseline: 1.0999x; 1.0999x over previous
//
#include <hip/hip_runtime.h>
#include <hip/hip_bf16.h>

// ELA forward on MI355X.
//  pack_x           : x fp32 -> bf16 seq in MFMA A-fragment tile order (staged in d_out)
//  pack_B           : {W} fp32 -> bf16 MFMA B-fragment [nb][kc] tile order (for pre_gemm)
//  pack_R           : {R} fp32 -> bf16 B-fragments, UNIT-CONTIGUOUS [nt][kc][i][lane][8]
//  pre_gemm_packed  : pre = seq @ W{1,2}; all-bf16, global_load_lds both operands
//  step_kernel x48  : BALANCED: 768 blocks x 256 thr (exactly 3 blocks/CU). Each block =
//                     half a unit's K (48 kc, 192KB of R) -> every CU streams 576KB/step
//                     (old layout: 128 CUs carried 768KB -> critical path). K-half-1 block
//                     publishes its partial G via system-scope relaxed stores + release
//                     flag (round-8-proven cross-XCD pattern); K-half-0 block spins
//                     (bounded, partners guaranteed co-resident), adds, does gates.
//  conv_gn_kernel   : grouped conv1d + GroupNorm + sigmoid
//  final_kernel     : out = xh[b,c,i] * xw[b,c,j] * x[b,c,i,j]
//
// HARD CONSTRAINTS (learned):
//  - round 1: NEVER write input buffers (d_in[*]) — harness replays without restoring.
//  - rounds 4-8: persistent/coop step loses to multi-launch (grid.sync ~93us; custom
//    grid barriers force L2/L3 refetch of R). Multi-launch + pair-local sync only.
//  - Per-CU miss-queue limits unique-stream reads to ~16-20 GB/s/CU: balance bytes/CU.

typedef float  f32x4 __attribute__((ext_vector_type(4)));
typedef __bf16 v8bf  __attribute__((ext_vector_type(8)));
typedef __bf16 v4bf  __attribute__((ext_vector_type(4)));

#define MFMA16(a, b, c) __builtin_amdgcn_mfma_f32_16x16x32_bf16((a), (b), (c), 0, 0, 0)

// ---- ws layout (bytes). Base block = 40.1 MB. Packs appended (ws >= 191MB verified). ----
static constexpr size_t OFF_PREP = 0;            // bf16 pre, C-frag order: 2*48*768*64*4
static constexpr size_t SZ_PREP  = 37748736;
static constexpr size_t OFF_H0   = 37748736;     // h ping (A-frag, 2 stacks): 2*96*64*8*2
static constexpr size_t OFF_H1   = 37945344;     // h pong
static constexpr size_t OFF_C    = 38141952;     // c state fp32: 2*192*64*4*4
static constexpr size_t OFF_N    = 38535168;
static constexpr size_t OFF_M    = 38928384;
static constexpr size_t OFF_YS   = 39321600;     // y sums fp32: 2*16*3072*4
static constexpr size_t OFF_GATE = 39714816;     // sigmoid gates fp32 (pre-steps: 384 flags)
static constexpr size_t BASE_END = 40108032;
static constexpr size_t SZ_RPACK = 75497472;     // one packed 3072x12288 bf16
static constexpr size_t OFF_RA   = BASE_END;     // W-pack lives here first, then R-pack
static constexpr size_t OFF_RB   = BASE_END + SZ_RPACK;
static constexpr size_t END_A    = OFF_RB + SZ_RPACK;   // 191,102,976

__device__ __forceinline__ void gl_lds16(const void* g, void* l) {
    __builtin_amdgcn_global_load_lds(
        (const __attribute__((address_space(1))) unsigned int*)g,
        (__attribute__((address_space(3))) unsigned int*)l, 16, 0, 0);
}

__global__ __launch_bounds__(256) void zero_kernel(f32x4* __restrict__ p, int n) {
    int i = blockIdx.x * 256 + threadIdx.x;
    if (i < n) { f32x4 z = 0.0f; p[i] = z; }
}

// x[16,64,48,48] -> seq A-pack: [mb 6][kc 96][sub 8][lane 64][8] bf16, row r = t*16+b
__global__ __launch_bounds__(256) void pack_x_kernel(const float* __restrict__ x,
                                                     __bf16* __restrict__ dst) {
    int gi = blockIdx.x * 256 + threadIdx.x;   // < 294912
    int lane = gi & 63;
    int rest = gi >> 6;
    int sub = rest & 7; rest >>= 3;
    int kc = rest % 96, mb = rest / 96;
    int r = mb * 128 + sub * 16 + (lane & 15);
    int t = r >> 4, b = r & 15;
    int k = kc * 32 + (lane >> 4) * 8;
    const f32x4* s = (const f32x4*)(x + (size_t)b * 147456 + (size_t)t * 3072 + k);
    f32x4 v0 = s[0], v1 = s[1];
    v8bf o;
#pragma unroll
    for (int j = 0; j < 4; ++j) { o[j] = (__bf16)v0[j]; o[4 + j] = (__bf16)v1[j]; }
    ((v8bf*)dst)[gi] = o;
}

// [3072,12288] fp32 -> B-pack [nb 96][kc 96][sub 8][lane 64][8] bf16 (via LDS transpose)
__global__ __launch_bounds__(256) void pack_B_kernel(const float* __restrict__ src0,
                                                     const float* __restrict__ src1,
                                                     __bf16* __restrict__ dst0,
                                                     __bf16* __restrict__ dst1) {
    int nb = blockIdx.x, kc = blockIdx.y, m = blockIdx.z;
    const float* src = m ? src1 : src0;
    __bf16* dst = m ? dst1 : dst0;
    int tid = threadIdx.x;
    __shared__ float tile[32][133];
    int kr = tid >> 3, nc0 = (tid & 7) * 16;
    const f32x4* s4 = (const f32x4*)(src + (size_t)(kc * 32 + kr) * 12288 + nb * 128 + nc0);
    f32x4 v0 = s4[0], v1 = s4[1], v2 = s4[2], v3 = s4[3];
#pragma unroll
    for (int r = 0; r < 4; ++r) {
        tile[kr][nc0 + r]      = v0[r];
        tile[kr][nc0 + 4 + r]  = v1[r];
        tile[kr][nc0 + 8 + r]  = v2[r];
        tile[kr][nc0 + 12 + r] = v3[r];
    }
    __syncthreads();
    __bf16* db = dst + (size_t)(nb * 96 + kc) * 4096;
#pragma unroll
    for (int c = 0; c < 2; ++c) {
        int lidx = tid * 2 + c;
        int sub = lidx >> 6, lane = lidx & 63;
        int kb = (lane >> 4) * 8, nn = sub * 16 + (lane & 15);
        v8bf o;
#pragma unroll
        for (int j = 0; j < 8; ++j) o[j] = (__bf16)tile[kb + j][nn];
        ((v8bf*)db)[lidx] = o;
    }
}

// [3072,12288] fp32 -> R-pack, UNIT-CONTIGUOUS: v8bf index ((nt*96+kc)*4+i)*64+lane,
// where column-tile ct = nb*8+sub = i*192+nt.
__global__ __launch_bounds__(256) void pack_R_kernel(const float* __restrict__ src0,
                                                     const float* __restrict__ src1,
                                                     __bf16* __restrict__ dst0,
                                                     __bf16* __restrict__ dst1) {
    int nb = blockIdx.x, kc = blockIdx.y, m = blockIdx.z;
    const float* src = m ? src1 : src0;
    __bf16* dst = m ? dst1 : dst0;
    int tid = threadIdx.x;
    __shared__ float tile[32][133];
    int kr = tid >> 3, nc0 = (tid & 7) * 16;
    const f32x4* s4 = (const f32x4*)(src + (size_t)(kc * 32 + kr) * 12288 + nb * 128 + nc0);
    f32x4 v0 = s4[0], v1 = s4[1], v2 = s4[2], v3 = s4[3];
#pragma unroll
    for (int r = 0; r < 4; ++r) {
        tile[kr][nc0 + r]      = v0[r];
        tile[kr][nc0 + 4 + r]  = v1[r];
        tile[kr][nc0 + 8 + r]  = v2[r];
        tile[kr][nc0 + 12 + r] = v3[r];
    }
    __syncthreads();
#pragma unroll
    for (int c = 0; c < 2; ++c) {
        int lidx = tid * 2 + c;
        int sub = lidx >> 6, lane = lidx & 63;
        int kb = (lane >> 4) * 8, nn = sub * 16 + (lane & 15);
        v8bf o;
#pragma unroll
        for (int j = 0; j < 8; ++j) o[j] = (__bf16)tile[kb + j][nn];
        int ct = nb * 8 + sub;
        int nt = ct % 192, fi = ct / 192;
        size_t off = (((size_t)nt * 96 + kc) * 4 + fi) * 64 + lane;
        ((v8bf*)dst)[off] = o;
    }
}

// pre = seq @ W, 128x128 tile, BK=32, BOTH operands pre-packed bf16 via global_load_lds.
__global__ __launch_bounds__(256) void pre_gemm_packed(const __bf16* __restrict__ Apack,
                                                       const __bf16* __restrict__ Bp0,
                                                       const __bf16* __restrict__ Bp1,
                                                       __bf16* __restrict__ preP) {
    int nb = blockIdx.x, mb = blockIdx.y, stack = blockIdx.z;
    const char* Bpack = (const char*)(stack ? Bp1 : Bp0);
    int tid = threadIdx.x, wave = tid >> 6, lane = tid & 63;
    __shared__ alignas(16) __bf16 As[4096];
    __shared__ alignas(16) __bf16 Bs[4096];
    f32x4 acc[4][4];
#pragma unroll
    for (int i = 0; i < 4; ++i)
#pragma unroll
        for (int j = 0; j < 4; ++j) acc[i][j] = 0.0f;

    for (int kc = 0; kc < 96; ++kc) {
        size_t atile = (size_t)(mb * 96 + kc) * 8192;
        size_t btile = (size_t)(nb * 96 + kc) * 8192;
        int chunk = wave * 2048;
        gl_lds16((const char*)Apack + atile + chunk + lane * 16,        (char*)As + chunk);
        gl_lds16((const char*)Apack + atile + chunk + 1024 + lane * 16, (char*)As + chunk + 1024);
        gl_lds16(Bpack + btile + chunk + lane * 16,        (char*)Bs + chunk);
        gl_lds16(Bpack + btile + chunk + 1024 + lane * 16, (char*)Bs + chunk + 1024);
        __syncthreads();
        const v8bf* A8 = (const v8bf*)As;
        const v8bf* B8 = (const v8bf*)Bs;
        v8bf a[4], b[4];
#pragma unroll
        for (int mi = 0; mi < 4; ++mi) a[mi] = A8[((wave >> 1) * 4 + mi) * 64 + lane];
#pragma unroll
        for (int ni = 0; ni < 4; ++ni) b[ni] = B8[((wave & 1) * 4 + ni) * 64 + lane];
#pragma unroll
        for (int mi = 0; mi < 4; ++mi)
#pragma unroll
            for (int ni = 0; ni < 4; ++ni) acc[mi][ni] = MFMA16(a[mi], b[ni], acc[mi][ni]);
        __syncthreads();
    }
#pragma unroll
    for (int mi = 0; mi < 4; ++mi)
#pragma unroll
        for (int ni = 0; ni < 4; ++ni) {
            int mt = mb * 8 + (wave >> 1) * 4 + mi;   // == t
            int nt4 = nb * 8 + (wave & 1) * 4 + ni;   // n-tile in [0,768)
            v4bf o;
#pragma unroll
            for (int r = 0; r < 4; ++r) o[r] = (__bf16)acc[mi][ni][r];
            ((v4bf*)preP)[(((size_t)stack * 48 + mt) * 768 + nt4) * 64 + lane] = o;
        }
}

// Fallback (small ws): pre = seq @ W with W read as fp32 (transpose+cvt in LDS).
__global__ __launch_bounds__(256) void pre_gemm(const __bf16* __restrict__ Apack,
                                                const float* __restrict__ W1,
                                                const float* __restrict__ W2,
                                                __bf16* __restrict__ preP) {
    int nb = blockIdx.x, mb = blockIdx.y, stack = blockIdx.z;
    const float* W = stack ? W2 : W1;
    int tid = threadIdx.x, wave = tid >> 6, lane = tid & 63;
    __shared__ alignas(16) __bf16 As[4096];
    __shared__ alignas(16) __bf16 Bs[4096];
    __shared__ float tile[32][133];
    f32x4 acc[4][4];
#pragma unroll
    for (int i = 0; i < 4; ++i)
#pragma unroll
        for (int j = 0; j < 4; ++j) acc[i][j] = 0.0f;

    int kr = tid >> 3, nc0 = (tid & 7) * 16;
    for (int kc = 0; kc < 96; ++kc) {
        size_t atile = (size_t)(mb * 96 + kc) * 8192;
        int chunk = wave * 2048;
        gl_lds16((const char*)Apack + atile + chunk + lane * 16,        (char*)As + chunk);
        gl_lds16((const char*)Apack + atile + chunk + 1024 + lane * 16, (char*)As + chunk + 1024);
        const f32x4* s4 = (const f32x4*)(W + (size_t)(kc * 32 + kr) * 12288 + nb * 128 + nc0);
        f32x4 v0 = s4[0], v1 = s4[1], v2 = s4[2], v3 = s4[3];
#pragma unroll
        for (int r = 0; r < 4; ++r) {
            tile[kr][nc0 + r]      = v0[r];
            tile[kr][nc0 + 4 + r]  = v1[r];
            tile[kr][nc0 + 8 + r]  = v2[r];
            tile[kr][nc0 + 12 + r] = v3[r];
        }
        __syncthreads();
#pragma unroll
        for (int c = 0; c < 2; ++c) {
            int lidx = tid * 2 + c;
            int sub = lidx >> 6, l2 = lidx & 63;
            int kb = (l2 >> 4) * 8, nn = sub * 16 + (l2 & 15);
            v8bf o;
#pragma unroll
            for (int j = 0; j < 8; ++j) o[j] = (__bf16)tile[kb + j][nn];
            ((v8bf*)Bs)[lidx] = o;
        }
        __syncthreads();
        const v8bf* A8 = (const v8bf*)As;
        const v8bf* B8 = (const v8bf*)Bs;
        v8bf a[4], b[4];
#pragma unroll
        for (int mi = 0; mi < 4; ++mi) a[mi] = A8[((wave >> 1) * 4 + mi) * 64 + lane];
#pragma unroll
        for (int ni = 0; ni < 4; ++ni) b[ni] = B8[((wave & 1) * 4 + ni) * 64 + lane];
#pragma unroll
        for (int mi = 0; mi < 4; ++mi)
#pragma unroll
            for (int ni = 0; ni < 4; ++ni) acc[mi][ni] = MFMA16(a[mi], b[ni], acc[mi][ni]);
        __syncthreads();
    }
#pragma unroll
    for (int mi = 0; mi < 4; ++mi)
#pragma unroll
        for (int ni = 0; ni < 4; ++ni) {
            int mt = mb * 8 + (wave >> 1) * 4 + mi;
            int nt4 = nb * 8 + (wave & 1) * 4 + ni;
            v4bf o;
#pragma unroll
            for (int r = 0; r < 4; ++r) o[r] = (__bf16)acc[mi][ni][r];
            ((v4bf*)preP)[(((size_t)stack * 48 + mt) * 768 + nt4) * 64 + lane] = o;
        }
}

// One recurrence step, BALANCED. 768 blocks x 256 thr. Block bid: unit = bid>>1
// (stack = unit/192, nt = unit%192), half = bid&1 -> kc range [half*48, half*48+48).
// 4 waves x 12 kc, depth-1 prefetch (verified inner loop). half1 publishes partial G to
// Gbuf + release flag; half0 spins (pair-local, co-resident), adds, does gates.
__global__ __launch_bounds__(256) void step_kernel(
    const __bf16* __restrict__ Rp0, const __bf16* __restrict__ Rp1,
    const __bf16* __restrict__ hread, __bf16* __restrict__ hwrite,
    const __bf16* __restrict__ preP,
    const float* __restrict__ bias1, const float* __restrict__ bias2,
    float* __restrict__ cbuf, float* __restrict__ nbuf, float* __restrict__ mbuf,
    float* __restrict__ ysum, float* __restrict__ Gbuf, unsigned* __restrict__ flags,
    int t) {
    int bid = blockIdx.x;
    int unit = bid >> 1, half = bid & 1;
    int nt = unit % 192, stack = unit / 192;
    int tid = threadIdx.x, wave = tid >> 6, lane = tid & 63;
    const v8bf* Rp = (const v8bf*)(stack ? Rp1 : Rp0);
    const v8bf* hA = (const v8bf*)hread + (size_t)stack * 96 * 64;
    size_t base0 = (size_t)nt * 24576 + lane;      // unit slice start (v8bf units)
    int kcs = half * 48 + wave * 12;
    f32x4 acc[4];
#pragma unroll
    for (int i = 0; i < 4; ++i) acc[i] = 0.0f;

    // depth-1 prefetch over the wave's contiguous 48KB run (verified rounds 7)
    v8bf a0 = hA[(size_t)kcs * 64 + lane];
    v8bf bf[4];
#pragma unroll
    for (int i = 0; i < 4; ++i) bf[i] = Rp[base0 + (size_t)kcs * 256 + i * 64];
    for (int kk = 0; kk < 12; ++kk) {
        v8bf a1 = a0;
        v8bf bn[4];
        if (kk < 11) {
            int kc1 = kcs + kk + 1;
            a1 = hA[(size_t)kc1 * 64 + lane];
#pragma unroll
            for (int i = 0; i < 4; ++i) bn[i] = Rp[base0 + (size_t)kc1 * 256 + i * 64];
        } else {
#pragma unroll
            for (int i = 0; i < 4; ++i) bn[i] = bf[i];
        }
#pragma unroll
        for (int i = 0; i < 4; ++i) acc[i] = MFMA16(a0, bf[i], acc[i]);
        a0 = a1;
#pragma unroll
        for (int i = 0; i < 4; ++i) bf[i] = bn[i];
    }

    __shared__ f32x4 red4[4][4][64];
#pragma unroll
    for (int i = 0; i < 4; ++i) red4[wave][i][lane] = acc[i];
    __syncthreads();

    if (wave == 0) {
        f32x4 g[4];
#pragma unroll
        for (int i = 0; i < 4; ++i) {
            f32x4 s = red4[0][i][lane];
#pragma unroll
            for (int w = 1; w < 4; ++w) s += red4[w][i][lane];
            g[i] = s;
        }
        if (half == 1) {
            // publish partial (system-scope relaxed -> L3, round-8-proven), then flag.
#pragma unroll
            for (int i = 0; i < 4; ++i)
#pragma unroll
                for (int r = 0; r < 4; ++r)
                    __hip_atomic_store(
                        Gbuf + ((((size_t)unit * 4 + i) * 64 + lane) * 4 + r), g[i][r],
                        __ATOMIC_RELAXED, __HIP_MEMORY_SCOPE_SYSTEM);
            if (lane == 0)
                __hip_atomic_fetch_add(flags + unit, 1u, __ATOMIC_RELEASE,
                                       __HIP_MEMORY_SCOPE_SYSTEM);
            return;
        }
        // half == 0: wait for partner's partial (pair-local spin; partner co-resident).
        {
            unsigned tgt = (unsigned)(t + 1);
            int guard = 0;
            while (__hip_atomic_load(flags + unit, __ATOMIC_RELAXED,
                                     __HIP_MEMORY_SCOPE_SYSTEM) < tgt) {
                __builtin_amdgcn_s_sleep(2);
                if (++guard > 10000000) break;   // finite safety valve (never hangs bench)
            }
            asm volatile("" ::: "memory");       // keep Gbuf reads below the spin
        }
#pragma unroll
        for (int i = 0; i < 4; ++i)
#pragma unroll
            for (int r = 0; r < 4; ++r)
                g[i][r] += __hip_atomic_load(
                    Gbuf + ((((size_t)unit * 4 + i) * 64 + lane) * 4 + r),
                    __ATOMIC_RELAXED, __HIP_MEMORY_SCOPE_SYSTEM);

        const float* bias = stack ? bias2 : bias1;
        int fcol = nt * 16 + (lane & 15);
        int bq = (lane >> 4) * 4;
#pragma unroll
        for (int i = 0; i < 4; ++i) {
            v4bf pv = ((const v4bf*)preP)[(((size_t)stack * 48 + t) * 768 + (i * 192 + nt)) * 64 + lane];
            float bv = bias[i * 3072 + fcol];
#pragma unroll
            for (int r = 0; r < 4; ++r) g[i][r] += (float)pv[r] + bv;
        }
        size_t sidx = ((size_t)stack * 192 + nt) * 64 + lane;
        f32x4 cc = ((f32x4*)cbuf)[sidx];
        f32x4 nn = ((f32x4*)nbuf)[sidx];
        f32x4 mm = ((f32x4*)mbuf)[sidx];
        int kc = fcol >> 5, ko = fcol & 31;
        __bf16* hw = hwrite + ((size_t)stack * 96 + kc) * 512 + (size_t)(ko >> 3) * 128 + (ko & 7);
        int flat = t * 3072 + fcol;
        int cch = flat / 2304;
        int rem = flat - cch * 2304;
        int u = rem / 48;
        int v = rem - u * 48;
        int yidx = cch * 48 + (stack ? u : v);
        float* yb = ysum + (size_t)stack * 16 * 3072;
#pragma unroll
        for (int r = 0; r < 4; ++r) {
            int brow = bq + r;
            float it = g[0][r], ft = g[1][r], zt = g[2][r], ot = g[3][r];
            float mnew = fmaxf(ft + mm[r], it);
            float iv = __expf(it - mnew);
            float fv = __expf(ft + mm[r] - mnew);
            float cnew = fv * cc[r] + iv * tanhf(zt);
            float nnew = fv * nn[r] + iv;
            float sg = 1.0f / (1.0f + __expf(-ot));
            float h = sg * cnew / (nnew + 1e-6f);
            cc[r] = cnew; nn[r] = nnew; mm[r] = mnew;
            hw[(size_t)brow * 8] = (__bf16)h;
            atomicAdd(yb + (size_t)brow * 3072 + yidx, h);
        }
        ((f32x4*)cbuf)[sidx] = cc;
        ((f32x4*)nbuf)[sidx] = nn;
        ((f32x4*)mbuf)[sidx] = mm;
    }
}

// grouped conv1d (K=5, 8 groups of 8ch) + GroupNorm(16 groups) + sigmoid, per (which, b)
__global__ __launch_bounds__(256) void conv_gn_kernel(const float* __restrict__ ysum,
                                                      const float* __restrict__ cw,
                                                      const float* __restrict__ gamma,
                                                      const float* __restrict__ beta,
                                                      float* __restrict__ gatebuf) {
    int bi = blockIdx.x;
    int s = bi >> 4, b = bi & 15;
    int tid = threadIdx.x;
    __shared__ float in0[3072], cvout[3072], cws[2560];
    __shared__ float r1[16][16], r2[16][16], mu_s[16], rs_s[16];
    const float* src = ysum + (size_t)(s * 16 + b) * 3072;
    for (int e = tid; e < 3072; e += 256) in0[e] = src[e] * (1.0f / 48.0f);
    for (int e = tid; e < 2560; e += 256) cws[e] = cw[e];
    __syncthreads();
    for (int e = tid; e < 3072; e += 256) {
        int co = e / 48, p = e - co * 48;
        int g = co >> 3;
        const float* wrow = cws + co * 40;
        const float* irow = in0 + g * 8 * 48;
        float a = 0.f;
#pragma unroll
        for (int ci = 0; ci < 8; ++ci)
#pragma unroll
            for (int q = 0; q < 5; ++q) {
                int pp = p + q - 2;
                if (pp >= 0 && pp < 48) a += wrow[ci * 5 + q] * irow[ci * 48 + pp];
            }
        cvout[e] = a;
    }
    __syncthreads();
    int gn = tid >> 4, ln = tid & 15;
    float s1 = 0.f, s2 = 0.f;
    for (int ii = ln; ii < 192; ii += 16) {
        float v = cvout[gn * 192 + ii];
        s1 += v; s2 += v * v;
    }
    r1[gn][ln] = s1; r2[gn][ln] = s2;
    __syncthreads();
    if (tid < 16) {
        float a = 0.f, c2 = 0.f;
        for (int ii = 0; ii < 16; ++ii) { a += r1[tid][ii]; c2 += r2[tid][ii]; }
        float mu = a * (1.0f / 192.0f);
        float var = c2 * (1.0f / 192.0f) - mu * mu;
        mu_s[tid] = mu;
        rs_s[tid] = rsqrtf(var + 1e-5f);
    }
    __syncthreads();
    float* dst = gatebuf + (size_t)(s * 16 + b) * 3072;
    for (int e = tid; e < 3072; e += 256) {
        int c = e / 48;
        int gg = c >> 2;
        float xn = (cvout[e] - mu_s[gg]) * rs_s[gg] * gamma[c] + beta[c];
        dst[e] = 1.0f / (1.0f + __expf(-xn));
    }
}

__global__ __launch_bounds__(256) void final_kernel(const float* __restrict__ x,
                                                    const float* __restrict__ gatebuf,
                                                    float* __restrict__ out) {
    int gid = blockIdx.x * 256 + threadIdx.x;  // < 589824 float4s
    int wi4 = gid % 12;
    int rest = gid / 12;
    int hi = rest % 48;
    int bc = rest / 48;
    int b = bc >> 6, c = bc & 63;
    f32x4 xv = ((const f32x4*)x)[gid];
    float gh = gatebuf[(size_t)(16 + b) * 3072 + c * 48 + hi];        // s=1 (y2) -> x_h[hi]
    f32x4 gw = *(const f32x4*)(gatebuf + (size_t)b * 3072 + c * 48 + wi4 * 4);  // s=0 -> x_w[wi]
    f32x4 o;
#pragma unroll
    for (int k = 0; k < 4; ++k) o[k] = xv[k] * gh * gw[k];
    ((f32x4*)out)[gid] = o;
}

extern "C" void kernel_launch(void* const* d_in, const int* in_sizes, int n_in,
                              void* d_out, int out_size, void* d_ws, size_t ws_size,
                              hipStream_t stream) {
    const float* x     = (const float*)d_in[0];
    const float* W1    = (const float*)d_in[1];
    const float* R1    = (const float*)d_in[2];
    const float* b1    = (const float*)d_in[3];
    const float* W2    = (const float*)d_in[4];
    const float* R2    = (const float*)d_in[5];
    const float* b2    = (const float*)d_in[6];
    const float* cw    = (const float*)d_in[7];
    const float* gamma = (const float*)d_in[8];
    const float* beta  = (const float*)d_in[9];

    char* ws = (char*)d_ws;
    __bf16* seqA = (__bf16*)d_out;               // scratch; dead after pre_gemm
    __bf16* preP = (__bf16*)(ws + OFF_PREP);
    __bf16* h0   = (__bf16*)(ws + OFF_H0);
    __bf16* h1   = (__bf16*)(ws + OFF_H1);
    float* cbuf  = (float*)(ws + OFF_C);
    float* nbuf  = (float*)(ws + OFF_N);
    float* mbuf  = (float*)(ws + OFF_M);
    float* ysum  = (float*)(ws + OFF_YS);
    float* gate  = (float*)(ws + OFF_GATE);
    unsigned* flags = (unsigned*)(ws + OFF_GATE); // 384 u32; gate region used post-steps
    float* gbuf  = (float*)d_out;                 // 1.5MB partial-G buffer (seqA dead)

    bool big_ws = ws_size >= END_A;   // verified on harness (rounds 0/2/3/4/6/7/8)
    __bf16* PA = (__bf16*)(ws + OFF_RA);   // pack region (time-shared: W-pack then R-pack)
    __bf16* PB = (__bf16*)(ws + OFF_RB);

    pack_x_kernel<<<1152, 256, 0, stream>>>(x, seqA);
    if (big_ws) {
        pack_B_kernel<<<dim3(96, 96, 2), 256, 0, stream>>>(W1, W2, PA, PB);
        pre_gemm_packed<<<dim3(96, 6, 2), 256, 0, stream>>>(seqA, PA, PB, preP);
        pack_R_kernel<<<dim3(96, 96, 2), 256, 0, stream>>>(R1, R2, PA, PB);
    } else {
        pre_gemm<<<dim3(96, 6, 2), 256, 0, stream>>>(seqA, W1, W2, preP);
        pack_R_kernel<<<dim3(96, 96, 2), 256, 0, stream>>>(R1, R2, PA, PB);
    }
    // zero h0/h1/c/n/m/ysum AND the 384 flag words (1536B past OFF_GATE start)
    zero_kernel<<<481, 256, 0, stream>>>((f32x4*)(ws + OFF_H0), 122976);

    for (int t = 0; t < 48; ++t) {
        const __bf16* hr = (t & 1) ? h1 : h0;
        __bf16* hw       = (t & 1) ? h0 : h1;
        step_kernel<<<768, 256, 0, stream>>>(PA, PB, hr, hw, preP, b1, b2,
                                             cbuf, nbuf, mbuf, ysum, gbuf, flags, t);
    }
    conv_gn_kernel<<<32, 256, 0, stream>>>(ysum, cw, gamma, beta, gate);
    final_kernel<<<2304, 256, 0, stream>>>(x, gate, (float*)d_out);
}